// Round 2
// baseline (355.741 us; speedup 1.0000x reference)
//
#include <hip/hip_runtime.h>

// out[g] = b + sum_k h[k] * <v_k, y>_g, where y = X @ W^T (per-node scalar),
// v_0 = ones, v_{k+1} = A^T v_k computed as an edge scatter:
//   per edge e: v_next[src_global[e]] += v_cur[dst_global[e]]
// edge_index row0 = g*N+dst (row of A), row1 = g*N+src (col of A); A[dst,src]+=1.
// 1^T A^k X W^T == <(A^T)^k 1, X W^T> -- exact same math, O(E) per power step.
//
// Scratch lives in static __device__ globals (NOT d_ws): round-1 abort was a
// GPU memory fault, most likely d_ws smaller than the 394 KB I assumed.
// Every element of these arrays is rewritten on every call (no cross-call state).

#define BN_MAX 32768   // B*N for this problem (32*1024)
#define DOTS_MAX 256   // L*B (8*32)

__device__ float g_y[BN_MAX];
__device__ float g_v[2][BN_MAX];
__device__ float g_dots[DOTS_MAX];

__global__ void k_init(const float* __restrict__ x, const float* __restrict__ W,
                       int BN, int F) {
    int i = blockIdx.x * blockDim.x + threadIdx.x;
    if (i < BN) {
        const float* xr = x + (size_t)i * F;
        float s = 0.f;
        #pragma unroll 8
        for (int f = 0; f < F; ++f) s += xr[f] * W[f];
        g_y[i]    = s;
        g_v[0][i] = 1.0f;   // v_0 = ones
        g_v[1][i] = 0.0f;
    }
}

// One block per graph: dots[k][g] = sum_j v_cur*y, and zero v_next
// (v_next's stale contents are v_{k-1}; this k's scatter fills it next).
__global__ void k_dot(int cur, int N, int k, int B) {
    int g = blockIdx.x;
    int base = g * N;
    const float* __restrict__ vc = g_v[cur];
    float*       __restrict__ vn = g_v[cur ^ 1];
    float s = 0.f;
    for (int j = threadIdx.x; j < N; j += blockDim.x) {
        s += vc[base + j] * g_y[base + j];
        vn[base + j] = 0.0f;
    }
    #pragma unroll
    for (int off = 32; off > 0; off >>= 1) s += __shfl_down(s, off);
    __shared__ float sm[4];                 // 256 threads = 4 waves
    if ((threadIdx.x & 63) == 0) sm[threadIdx.x >> 6] = s;
    __syncthreads();
    if (threadIdx.x == 0)
        g_dots[k * B + g] = sm[0] + sm[1] + sm[2] + sm[3];
}

__global__ void k_scatter(const int* __restrict__ dst_g, const int* __restrict__ src_g,
                          int cur, int E, int BN) {
    int e = blockIdx.x * blockDim.x + threadIdx.x;
    if (e < E) {
        int di = dst_g[e];
        int si = src_g[e];
        // clamp-guard: garbage indices -> wrong answer (diagnosable), not a GPU fault
        if ((unsigned)di < (unsigned)BN && (unsigned)si < (unsigned)BN)
            atomicAdd(&g_v[cur ^ 1][si], g_v[cur][di]);
    }
}

__global__ void k_out(const float* __restrict__ h, const float* __restrict__ b,
                      float* __restrict__ out, int B, int L) {
    int g = blockIdx.x * blockDim.x + threadIdx.x;
    if (g < B) {
        float s = b[0];
        for (int k = 0; k < L; ++k) s += h[k] * g_dots[k * B + g];
        out[g] = s;
    }
}

extern "C" void kernel_launch(void* const* d_in, const int* in_sizes, int n_in,
                              void* d_out, int out_size, void* d_ws, size_t ws_size,
                              hipStream_t stream) {
    const float* x  = (const float*)d_in[0];
    const int*   ei = (const int*)d_in[1];   // (2, E): row0=dst global, row1=src global
    // d_in[2] = batch (unused: equal-size graphs)
    const float* h  = (const float*)d_in[3];
    const float* W  = (const float*)d_in[4];
    const float* b  = (const float*)d_in[5];
    float* out = (float*)d_out;

    const int BN = in_sizes[2];          // B*N = 32768
    const int L  = in_sizes[3];          // 8
    const int F  = in_sizes[4];          // 32
    const int E  = in_sizes[1] / 2;      // 524288
    const int B  = out_size;             // 32
    const int N  = BN / B;               // 1024

    if (BN > BN_MAX || L * B > DOTS_MAX) return;  // fixed-shape problem; never taken

    const int* dst_g = ei;
    const int* src_g = ei + E;

    k_init<<<(BN + 255) / 256, 256, 0, stream>>>(x, W, BN, F);

    int cur = 0;
    for (int k = 0; k < L; ++k) {
        k_dot<<<B, 256, 0, stream>>>(cur, N, k, B);
        if (k < L - 1) {
            k_scatter<<<(E + 255) / 256, 256, 0, stream>>>(dst_g, src_g, cur, E, BN);
            cur ^= 1;
        }
    }

    k_out<<<1, 64, 0, stream>>>(h, b, out, B, L);
}

// Round 4
// 273.206 us; speedup vs baseline: 1.3021x; 1.3021x over previous
//
#include <hip/hip_runtime.h>

// out[g] = b + sum_k h[k] * <v_k, y>_g, y = X @ W^T (scalar per node),
// v_0 = 1, v_{k+1} = A^T v_k  (per edge: v_next[src] += v_cur[dst]).
// The iteration is block-diagonal per graph -> bucket edges by graph once,
// then one workgroup per graph runs all L steps in LDS with __syncthreads only.
//
// R3 bug (fixed): scatter had operands swapped (v_next[dst] += v_cur[src] = A*v,
// not A^T*v). pk packs (dst_local<<16)|src_local; correct scatter is
//   v_next[pk & 0xffff] += v_cur[pk >> 16].
//
// Bucketing uses per-(block,graph) private regions: no global atomics, no
// zero-init kernel. Capacity 128 vs Binomial(2048,1/32) mean 64 (8 sigma),
// overflow-guarded. All scratch is static __device__ (d_ws unused); every
// element read is written earlier in the same call.

#define NB      256    // bucketizer blocks
#define CAP_PB  128    // slots per (block, graph)
#define BMAX    32
#define NMAX    1024

__device__ unsigned g_bucket[NB * BMAX * CAP_PB];   // 4 MB
__device__ int      g_cnt[NB * BMAX];

__global__ void k_bucket(const int* __restrict__ dst_g, const int* __restrict__ src_g,
                         int E, int N, int B) {
    __shared__ int lcur[BMAX];
    if (threadIdx.x < BMAX) lcur[threadIdx.x] = 0;
    __syncthreads();
    int per = (E + gridDim.x - 1) / gridDim.x;
    int s0 = blockIdx.x * per;
    int s1 = min(E, s0 + per);
    for (int e = s0 + (int)threadIdx.x; e < s1; e += blockDim.x) {
        int d = dst_g[e], s = src_g[e];
        int g = d / N;                       // edge's graph (src is in same graph)
        if ((unsigned)g < (unsigned)B) {
            int slot = atomicAdd(&lcur[g], 1);
            if (slot < CAP_PB)
                g_bucket[(blockIdx.x * BMAX + g) * CAP_PB + slot] =
                    ((unsigned)(d - g * N) << 16) | (unsigned)(s - g * N);
        }
    }
    __syncthreads();
    if (threadIdx.x < BMAX)
        g_cnt[blockIdx.x * BMAX + threadIdx.x] = min(lcur[threadIdx.x], CAP_PB);
}

// One block per graph; entire L-step power iteration in LDS.
__global__ __launch_bounds__(512) void
k_solve(const float* __restrict__ x, const float* __restrict__ h,
        const float* __restrict__ bias, const float* __restrict__ W,
        float* __restrict__ out, int N, int F, int L) {
    __shared__ float y[NMAX];
    __shared__ float v[2][NMAX];
    __shared__ float red[8];
    __shared__ int   lcnt[NB];
    __shared__ float lw[32];                 // F == 32

    const int g   = blockIdx.x;
    const int tid = threadIdx.x;

    if (tid < F) lw[tid] = W[tid];
    for (int i = tid; i < NB; i += blockDim.x) lcnt[i] = g_cnt[i * BMAX + g];
    __syncthreads();

    // y[node] = x[node] . W  -- 8 lanes per node, float4 loads (coalesced 1KB/wave)
    const int grp = tid >> 3, sub = tid & 7;         // 64 node-groups per pass
    for (int j0 = 0; j0 < N; j0 += 64) {
        int node = j0 + grp;
        const float4* row = (const float4*)(x + ((size_t)g * N + node) * F);
        float4 xv = row[sub];
        float  s  = xv.x * lw[sub * 4] + xv.y * lw[sub * 4 + 1] +
                    xv.z * lw[sub * 4 + 2] + xv.w * lw[sub * 4 + 3];
        s += __shfl_xor(s, 4, 8);
        s += __shfl_xor(s, 2, 8);
        s += __shfl_xor(s, 1, 8);
        if (sub == 0) y[node] = s;
    }
    for (int j = tid; j < N; j += blockDim.x) v[0][j] = 1.0f;
    __syncthreads();

    float acc = 0.0f;
    int cur = 0;
    for (int k = 0; k < L; ++k) {
        // dot_k = <v_cur, y>
        float p = 0.0f;
        for (int j = tid; j < N; j += blockDim.x) p += v[cur][j] * y[j];
        #pragma unroll
        for (int off = 32; off > 0; off >>= 1) p += __shfl_down(p, off);
        if ((tid & 63) == 0) red[tid >> 6] = p;
        __syncthreads();
        if (tid == 0) {
            float t = 0.0f;
            #pragma unroll
            for (int w = 0; w < 8; ++w) t += red[w];
            acc += h[k] * t;
        }
        if (k == L - 1) break;

        for (int j = tid; j < N; j += blockDim.x) v[cur ^ 1][j] = 0.0f;
        __syncthreads();
        // scatter: v_next[src_local] += v_cur[dst_local]  (pk = dst<<16 | src)
        for (int t = tid; t < NB * CAP_PB; t += blockDim.x) {
            int blk = t >> 7;                 // CAP_PB == 128
            int s   = t & (CAP_PB - 1);
            if (s < lcnt[blk]) {
                unsigned pk = g_bucket[(blk * BMAX + g) * CAP_PB + s];
                atomicAdd(&v[cur ^ 1][pk & 0xffffu], v[cur][pk >> 16]);
            }
        }
        __syncthreads();
        cur ^= 1;
    }
    if (tid == 0) out[g] = bias[0] + acc;
}

extern "C" void kernel_launch(void* const* d_in, const int* in_sizes, int n_in,
                              void* d_out, int out_size, void* d_ws, size_t ws_size,
                              hipStream_t stream) {
    const float* x  = (const float*)d_in[0];
    const int*   ei = (const int*)d_in[1];   // (2,E): row0 = dst global, row1 = src global
    const float* h  = (const float*)d_in[3];
    const float* W  = (const float*)d_in[4];
    const float* b  = (const float*)d_in[5];
    float* out = (float*)d_out;

    const int BN = in_sizes[2];          // 32768
    const int L  = in_sizes[3];          // 8
    const int F  = in_sizes[4];          // 32
    const int E  = in_sizes[1] / 2;      // 524288
    const int B  = out_size;             // 32
    const int N  = BN / B;               // 1024

    if (B > BMAX || N > NMAX || F != 32 || L > 8) return;  // fixed shapes; never taken

    const int* dst_g = ei;
    const int* src_g = ei + E;

    k_bucket<<<NB, 256, 0, stream>>>(dst_g, src_g, E, N, B);
    k_solve<<<B, 512, 0, stream>>>(x, h, b, W, out, N, F, L);
}

// Round 5
// 233.807 us; speedup vs baseline: 1.5215x; 1.1685x over previous
//
#include <hip/hip_runtime.h>

// out[g] = b + sum_k h[k] * <v_k, y>_g, y = X @ W^T (scalar per node),
// v_0 = 1, v_{k+1} = A^T v_k  (per edge: v_next[src] += v_cur[dst]).
// Bucket edges by graph once (per-(block,graph) private regions, no global
// atomics), then one workgroup per graph runs the whole L-step iteration with
// edges REGISTER-RESIDENT: the k-loop touches no global memory at all.
// R4 lesson: re-reading g_bucket every pass at 2 waves/SIMD was pure latency
// exposure (205 us, VALUBusy 1.1%).
//
// pk packs (dst_local<<16)|src_local; scatter is v_next[pk&0xffff] += v_cur[pk>>16].

#define NB      256    // bucketizer blocks
#define CAP_PB  128    // slots per (block, graph); mean fill 64, 8 sigma margin
#define BMAX    32
#define NMAX    1024
#define TPB     1024   // k_solve threads per block
#define SLOTS   ((NB * CAP_PB) / TPB)   // 32 register slots per thread
#define SENT    0xFFFFFFFFu

__device__ unsigned g_bucket[NB * BMAX * CAP_PB];   // 4 MB
__device__ int      g_cnt[NB * BMAX];

__global__ void k_bucket(const int* __restrict__ dst_g, const int* __restrict__ src_g,
                         int E, int nshift, int B) {
    __shared__ int lcur[BMAX];
    if (threadIdx.x < BMAX) lcur[threadIdx.x] = 0;
    __syncthreads();
    int per = (E + gridDim.x - 1) / gridDim.x;
    int s0 = blockIdx.x * per;
    int s1 = min(E, s0 + per);
    int N = 1 << nshift;
    for (int e = s0 + (int)threadIdx.x; e < s1; e += blockDim.x) {
        int d = dst_g[e], s = src_g[e];
        int g = d >> nshift;                 // edge's graph (src is in same graph)
        if ((unsigned)g < (unsigned)B) {
            int slot = atomicAdd(&lcur[g], 1);
            if (slot < CAP_PB)
                g_bucket[(blockIdx.x * BMAX + g) * CAP_PB + slot] =
                    ((unsigned)(d - (g << nshift)) << 16) | (unsigned)(s - (g << nshift));
        }
    }
    (void)N;
    __syncthreads();
    if (threadIdx.x < BMAX)
        g_cnt[blockIdx.x * BMAX + threadIdx.x] = min(lcur[threadIdx.x], CAP_PB);
}

// One block per graph; edges in registers; entire L-step iteration in LDS.
__global__ __launch_bounds__(TPB) void
k_solve(const float* __restrict__ x, const float* __restrict__ h,
        const float* __restrict__ bias, const float* __restrict__ W,
        float* __restrict__ out, int N, int F, int L) {
    __shared__ float y[NMAX];
    __shared__ float v[2][NMAX];
    __shared__ float red[16];
    __shared__ int   lcnt[NB];
    __shared__ float lw[32];                 // F == 32
    __shared__ float lh[8];                  // L <= 8

    const int g   = blockIdx.x;
    const int tid = threadIdx.x;

    if (tid < 32) lw[tid] = W[tid];
    if (tid < 8)  lh[tid] = (tid < L) ? h[tid] : 0.0f;
    for (int i = tid; i < NB; i += TPB) lcnt[i] = g_cnt[i * BMAX + g];
    __syncthreads();

    // one-time edge load into registers (sentinel for empty slots)
    unsigned ed[SLOTS];
    #pragma unroll
    for (int i = 0; i < SLOTS; ++i) {
        int t   = tid + i * TPB;
        int blk = t >> 7;                    // / CAP_PB
        int s   = t & (CAP_PB - 1);
        ed[i] = (s < lcnt[blk]) ? g_bucket[(blk * BMAX + g) * CAP_PB + s] : SENT;
    }

    // y[node] = x[node] . W  -- 8 lanes per node, float4 loads (coalesced)
    const int grp = tid >> 3, sub = tid & 7; // 128 node-groups per pass
    for (int j0 = 0; j0 < N; j0 += TPB / 8) {
        int node = j0 + grp;
        const float4* row = (const float4*)(x + ((size_t)g * N + node) * F);
        float4 xv = row[sub];
        float  s  = xv.x * lw[sub * 4] + xv.y * lw[sub * 4 + 1] +
                    xv.z * lw[sub * 4 + 2] + xv.w * lw[sub * 4 + 3];
        s += __shfl_xor(s, 4, 8);
        s += __shfl_xor(s, 2, 8);
        s += __shfl_xor(s, 1, 8);
        if (sub == 0) y[node] = s;
    }
    for (int j = tid; j < N; j += TPB) v[0][j] = 1.0f;
    __syncthreads();

    float acc = 0.0f;
    int cur = 0;
    for (int k = 0; k < L; ++k) {
        // per-thread partial of h[k] * <v_cur, y>; reduced once after the loop
        float p = 0.0f;
        for (int j = tid; j < N; j += TPB) p += v[cur][j] * y[j];
        acc += lh[k] * p;
        if (k == L - 1) break;

        for (int j = tid; j < N; j += TPB) v[cur ^ 1][j] = 0.0f;
        __syncthreads();                      // zeros visible before scatter
        float*       __restrict__ vn = v[cur ^ 1];
        const float* __restrict__ vc = v[cur];
        #pragma unroll
        for (int i = 0; i < SLOTS; ++i) {
            unsigned pk = ed[i];
            if (pk != SENT) atomicAdd(&vn[pk & 0xffffu], vc[pk >> 16]);
        }
        __syncthreads();                      // scatter complete before next dot
        cur ^= 1;
    }

    #pragma unroll
    for (int off = 32; off > 0; off >>= 1) acc += __shfl_down(acc, off);
    if ((tid & 63) == 0) red[tid >> 6] = acc;
    __syncthreads();
    if (tid == 0) {
        float t = 0.0f;
        #pragma unroll
        for (int w = 0; w < 16; ++w) t += red[w];
        out[g] = bias[0] + t;
    }
}

extern "C" void kernel_launch(void* const* d_in, const int* in_sizes, int n_in,
                              void* d_out, int out_size, void* d_ws, size_t ws_size,
                              hipStream_t stream) {
    const float* x  = (const float*)d_in[0];
    const int*   ei = (const int*)d_in[1];   // (2,E): row0 = dst global, row1 = src global
    const float* h  = (const float*)d_in[3];
    const float* W  = (const float*)d_in[4];
    const float* b  = (const float*)d_in[5];
    float* out = (float*)d_out;

    const int BN = in_sizes[2];          // 32768
    const int L  = in_sizes[3];          // 8
    const int F  = in_sizes[4];          // 32
    const int E  = in_sizes[1] / 2;      // 524288
    const int B  = out_size;             // 32
    const int N  = BN / B;               // 1024

    // fixed-shape guards (never taken for this problem)
    if (B > BMAX || N > NMAX || F != 32 || L > 8 || (N & (N - 1)) != 0) return;
    int nshift = 0;
    while ((1 << nshift) < N) ++nshift;

    const int* dst_g = ei;
    const int* src_g = ei + E;

    k_bucket<<<NB, 256, 0, stream>>>(dst_g, src_g, E, nshift, B);
    k_solve<<<B, TPB, 0, stream>>>(x, h, b, W, out, N, F, L);
}

// Round 6
// 115.152 us; speedup vs baseline: 3.0893x; 2.0304x over previous
//
#include <hip/hip_runtime.h>

// out[g] = b + sum_k h[k] * <u_k, y>_g, y = X @ W^T (scalar per node),
// u_0 = 1, u_{k+1} = A^T u_k. Per-node GATHER form: u'[s] = sum over in-edges
// (edges with src_local = s) of u[dst_local]. One thread per node, neighbor
// indices register-resident, values gathered from LDS -- NO atomics in the
// k-loop (R5 lesson: LDS float atomicAdd = CAS retry loop = dependent-latency
// disaster at low occupancy; 165 us with every pipe idle).
//
// CSR build: fixed 48 slots/node (Poisson(16) in-degree; P(deg>48)~1e-10/node),
// dead slots prefilled with index 1024 -> gather reads v[1024]=0 (self-masking).

#define BMAX   32
#define NMAX   1024
#define REG_E  48                 // per-node in-edge capacity
#define RE_U32 (REG_E / 2)        // 24 packed u32 per node
#define TPB    1024
#define DEADIDX 1024u

__device__ int g_deg[BMAX * NMAX];
__device__ __align__(16) unsigned short g_csr[BMAX * NMAX * REG_E];  // 3 MB

__global__ void k_init_csr(int n_deg, int n_csr32) {
    int i = blockIdx.x * blockDim.x + threadIdx.x;
    unsigned* c32 = (unsigned*)g_csr;
    if (i < n_csr32) c32[i] = (DEADIDX << 16) | DEADIDX;   // 0x04000400
    if (i < n_deg)   g_deg[i] = 0;
}

__global__ void k_fill(const int* __restrict__ dst_g, const int* __restrict__ src_g,
                       int E, int nmask) {
    int e = blockIdx.x * blockDim.x + threadIdx.x;
    if (e < E) {
        int sg = src_g[e];                       // owner node (global id)
        int pos = atomicAdd(&g_deg[sg], 1);      // int atomic: native & fast
        if (pos < REG_E)
            g_csr[(size_t)sg * REG_E + pos] = (unsigned short)(dst_g[e] & nmask);
    }
}

// One block per graph, one thread per node; whole L-step iteration in LDS,
// neighbor lists in registers, zero atomics.
__global__ __launch_bounds__(TPB) void
k_solve(const float* __restrict__ x, const float* __restrict__ h,
        const float* __restrict__ bias, const float* __restrict__ W,
        float* __restrict__ out, int N, int F, int L) {
    __shared__ float y[NMAX];
    __shared__ float v[2048];                // [0,1024) live, [1024,2048) zeros
    __shared__ float red[16];
    __shared__ float lw[32];                 // F == 32
    __shared__ float lh[8];                  // L <= 8

    const int g   = blockIdx.x;
    const int tid = threadIdx.x;
    const int gid = g * N + tid;

    if (tid < 32) lw[tid] = W[tid];
    if (tid < 8)  lh[tid] = (tid < L) ? h[tid] : 0.0f;

    // stage this node's neighbor list into registers (6 x uint4 = 96 B, coalesced)
    unsigned idx[RE_U32];
    {
        const uint4* cp = (const uint4*)(g_csr + (size_t)gid * REG_E);
        #pragma unroll
        for (int i = 0; i < 6; ++i) {
            uint4 t = cp[i];
            idx[4 * i + 0] = t.x; idx[4 * i + 1] = t.y;
            idx[4 * i + 2] = t.z; idx[4 * i + 3] = t.w;
        }
    }

    // y[node] = x[node] . W  -- 8 lanes per node, float4 loads (coalesced)
    const int grp = tid >> 3, sub = tid & 7;
    __syncthreads();                         // lw ready
    for (int j0 = 0; j0 < N; j0 += TPB / 8) {
        int node = j0 + grp;
        const float4* row = (const float4*)(x + ((size_t)g * N + node) * F);
        float4 xv = row[sub];
        float  s  = xv.x * lw[sub * 4] + xv.y * lw[sub * 4 + 1] +
                    xv.z * lw[sub * 4 + 2] + xv.w * lw[sub * 4 + 3];
        s += __shfl_xor(s, 4, 8);
        s += __shfl_xor(s, 2, 8);
        s += __shfl_xor(s, 1, 8);
        if (sub == 0) y[node] = s;
    }
    v[tid]        = 1.0f;                    // u_0 = ones
    v[1024 + tid] = 0.0f;                    // dead-index landing zone
    __syncthreads();

    const float yreg = y[tid];
    float vreg = 1.0f;
    float acc  = 0.0f;

    for (int k = 0; k < L; ++k) {
        acc += lh[k] * vreg * yreg;
        if (k == L - 1) break;

        float nv = 0.0f;
        #pragma unroll
        for (int i = 0; i < RE_U32; ++i) {   // 48 independent ds_read_b32
            unsigned p = idx[i];
            nv += v[p & 2047u];
            nv += v[(p >> 16) & 2047u];
        }
        __syncthreads();                     // all gathers done before overwrite
        v[tid] = nv;
        vreg   = nv;
        __syncthreads();                     // new v visible
    }

    #pragma unroll
    for (int off = 32; off > 0; off >>= 1) acc += __shfl_down(acc, off);
    if ((tid & 63) == 0) red[tid >> 6] = acc;
    __syncthreads();
    if (tid == 0) {
        float t = 0.0f;
        #pragma unroll
        for (int w = 0; w < 16; ++w) t += red[w];
        out[g] = bias[0] + t;
    }
}

extern "C" void kernel_launch(void* const* d_in, const int* in_sizes, int n_in,
                              void* d_out, int out_size, void* d_ws, size_t ws_size,
                              hipStream_t stream) {
    const float* x  = (const float*)d_in[0];
    const int*   ei = (const int*)d_in[1];   // (2,E): row0 = dst global, row1 = src global
    const float* h  = (const float*)d_in[3];
    const float* W  = (const float*)d_in[4];
    const float* b  = (const float*)d_in[5];
    float* out = (float*)d_out;

    const int BN = in_sizes[2];          // 32768
    const int L  = in_sizes[3];          // 8
    const int F  = in_sizes[4];          // 32
    const int E  = in_sizes[1] / 2;      // 524288
    const int B  = out_size;             // 32
    const int N  = BN / B;               // 1024

    // fixed-shape guards (never taken for this problem)
    if (B > BMAX || N != NMAX || F != 32 || L > 8) return;

    const int* dst_g = ei;
    const int* src_g = ei + E;

    const int n_csr32 = BMAX * NMAX * REG_E / 2;   // 786432 u32 prefills
    k_init_csr<<<(n_csr32 + 255) / 256, 256, 0, stream>>>(BN, n_csr32);
    k_fill<<<(E + 255) / 256, 256, 0, stream>>>(dst_g, src_g, E, N - 1);
    k_solve<<<B, TPB, 0, stream>>>(x, h, b, W, out, N, F, L);
}

// Round 7
// 114.145 us; speedup vs baseline: 3.1166x; 1.0088x over previous
//
#include <hip/hip_runtime.h>

// out[g] = b + sum_k h[k] * <u_k, y>_g, y = X @ W^T (scalar per node),
// u_0 = 1, u_{k+1} = A^T u_k. Per-node GATHER form: u'[s] = sum over in-edges
// (src_local = s) of u[dst_local]. One thread per node, neighbor indices
// register-resident, values gathered from LDS -- no atomics in the k-loop.
//
// R7 changes vs R6 (which passed, absmax 0.0):
//  - no 3 MB sentinel prefill: gather is masked by per-node degree instead;
//    stale CSR entries are address-clamped (&1023) and value-masked. Only
//    g_deg (128 KB) is zeroed.
//  - degree-masked unrolled gather: whole-wave execz skip past wave-max
//    degree (~28 of 48 slots) cuts ~40% of ds_read traffic.
//  - k_fill processes 4 edges/thread via int4 loads.

#define BMAX   32
#define NMAX   1024
#define REG_E  48                 // per-node in-edge capacity (Poisson(16); P(>48) ~ 1e-10)
#define RE_U32 (REG_E / 2)        // 24 packed u32 per node
#define TPB    1024

__device__ __align__(16) int            g_deg[BMAX * NMAX];          // 128 KB
__device__ __align__(16) unsigned short g_csr[BMAX * NMAX * REG_E];  // 3 MB (no prefill)

__global__ void k_zero() {                       // 32 blocks x 256: one int4 each
    int i = blockIdx.x * blockDim.x + threadIdx.x;
    ((int4*)g_deg)[i] = make_int4(0, 0, 0, 0);
}

__global__ void k_fill(const int* __restrict__ dst_g, const int* __restrict__ src_g,
                       int E, int nmask) {
    int t = blockIdx.x * blockDim.x + threadIdx.x;
    int base = t * 4;
    if (base < E) {                              // E % 4 == 0 (guarded in launcher)
        const int4 d4 = *(const int4*)(dst_g + base);
        const int4 s4 = *(const int4*)(src_g + base);
        int pos;
        pos = atomicAdd(&g_deg[s4.x], 1);
        if (pos < REG_E) g_csr[(size_t)s4.x * REG_E + pos] = (unsigned short)(d4.x & nmask);
        pos = atomicAdd(&g_deg[s4.y], 1);
        if (pos < REG_E) g_csr[(size_t)s4.y * REG_E + pos] = (unsigned short)(d4.y & nmask);
        pos = atomicAdd(&g_deg[s4.z], 1);
        if (pos < REG_E) g_csr[(size_t)s4.z * REG_E + pos] = (unsigned short)(d4.z & nmask);
        pos = atomicAdd(&g_deg[s4.w], 1);
        if (pos < REG_E) g_csr[(size_t)s4.w * REG_E + pos] = (unsigned short)(d4.w & nmask);
    }
}

// One block per graph, one thread per node; whole L-step iteration in LDS.
__global__ __launch_bounds__(TPB) void
k_solve(const float* __restrict__ x, const float* __restrict__ h,
        const float* __restrict__ bias, const float* __restrict__ W,
        float* __restrict__ out, int N, int F, int L) {
    __shared__ float y[NMAX];
    __shared__ float v[NMAX];
    __shared__ float red[16];
    __shared__ float lw[32];                 // F == 32
    __shared__ float lh[8];                  // L <= 8

    const int g   = blockIdx.x;
    const int tid = threadIdx.x;
    const int gid = g * NMAX + tid;

    // stage this node's neighbor list into registers (6 x uint4, coalesced)
    unsigned idx[RE_U32];
    {
        const uint4* cp = (const uint4*)(g_csr + (size_t)gid * REG_E);
        #pragma unroll
        for (int i = 0; i < 6; ++i) {
            uint4 t = cp[i];
            idx[4 * i + 0] = t.x; idx[4 * i + 1] = t.y;
            idx[4 * i + 2] = t.z; idx[4 * i + 3] = t.w;
        }
    }
    const int dc = min(g_deg[gid], REG_E);   // entries >= dc are stale: masked below

    if (tid < 32) lw[tid] = W[tid];
    if (tid < 8)  lh[tid] = (tid < L) ? h[tid] : 0.0f;
    __syncthreads();                         // lw ready

    // y[node] = x[node] . W  -- 8 lanes per node, float4 loads (coalesced)
    const int grp = tid >> 3, sub = tid & 7;
    for (int j0 = 0; j0 < N; j0 += TPB / 8) {
        int node = j0 + grp;
        const float4* row = (const float4*)(x + ((size_t)g * N + node) * F);
        float4 xv = row[sub];
        float  s  = xv.x * lw[sub * 4] + xv.y * lw[sub * 4 + 1] +
                    xv.z * lw[sub * 4 + 2] + xv.w * lw[sub * 4 + 3];
        s += __shfl_xor(s, 4, 8);
        s += __shfl_xor(s, 2, 8);
        s += __shfl_xor(s, 1, 8);
        if (sub == 0) y[node] = s;
    }
    v[tid] = 1.0f;                           // u_0 = ones
    __syncthreads();

    const float yreg = y[tid];
    float vreg = 1.0f;
    float acc  = 0.0f;

    for (int k = 0; k < L; ++k) {
        acc += lh[k] * vreg * yreg;
        if (k == L - 1) break;

        float nv = 0.0f;
        #pragma unroll
        for (int i = 0; i < RE_U32; ++i) {   // execz-skips past wave-max degree
            if (2 * i < dc) {
                unsigned p = idx[i];
                nv += v[p & 1023u];          // address clamped; value valid (2i<dc)
                float hv = v[(p >> 16) & 1023u];
                nv += (2 * i + 1 < dc) ? hv : 0.0f;
            }
        }
        __syncthreads();                     // all gathers done before overwrite
        v[tid] = nv;
        vreg   = nv;
        __syncthreads();                     // new v visible
    }

    #pragma unroll
    for (int off = 32; off > 0; off >>= 1) acc += __shfl_down(acc, off);
    if ((tid & 63) == 0) red[tid >> 6] = acc;
    __syncthreads();
    if (tid == 0) {
        float t = 0.0f;
        #pragma unroll
        for (int w = 0; w < 16; ++w) t += red[w];
        out[g] = bias[0] + t;
    }
}

extern "C" void kernel_launch(void* const* d_in, const int* in_sizes, int n_in,
                              void* d_out, int out_size, void* d_ws, size_t ws_size,
                              hipStream_t stream) {
    const float* x  = (const float*)d_in[0];
    const int*   ei = (const int*)d_in[1];   // (2,E): row0 = dst global, row1 = src global
    const float* h  = (const float*)d_in[3];
    const float* W  = (const float*)d_in[4];
    const float* b  = (const float*)d_in[5];
    float* out = (float*)d_out;

    const int BN = in_sizes[2];          // 32768
    const int L  = in_sizes[3];          // 8
    const int F  = in_sizes[4];          // 32
    const int E  = in_sizes[1] / 2;      // 524288
    const int B  = out_size;             // 32
    const int N  = BN / B;               // 1024

    // fixed-shape guards (never taken for this problem)
    if (B > BMAX || N != NMAX || F != 32 || L > 8 || (E & 3) != 0) return;

    const int* dst_g = ei;
    const int* src_g = ei + E;

    k_zero<<<BMAX * NMAX / (256 * 4), 256, 0, stream>>>();
    k_fill<<<(E / 4 + 255) / 256, 256, 0, stream>>>(dst_g, src_g, E, N - 1);
    k_solve<<<B, TPB, 0, stream>>>(x, h, b, W, out, N, F, L);
}